// Round 1
// 1551.436 us; speedup vs baseline: 1.2427x; 1.2427x over previous
//
#include <hip/hip_runtime.h>
#include <hip/hip_bf16.h>
#include <stdint.h>

// Qwen3 MoE sparse block: B=2,S=1024 -> T=2048 tokens, H=2048, I=768, E=64, top-8.
#define T_  2048
#define H_  2048
#define I_  768
#define E_  64
#define TK_ 16384   // T_*8 routed pairs

// GEMM tile config (both grouped GEMMs): 128x128 block tile, BK=32, 256 thr / 4 waves (2x2).
#define BM 128
#define BN 128
#define BK 32

// Max non-empty (expert, m-tile) descriptors: sum_e ceil(cnt_e/BM) <= TK_/BM + E_ = 128+64.
#define MAXTILES 192

typedef __attribute__((ext_vector_type(8))) short  short8;   // 8 bf16 = one MFMA A/B frag
typedef __attribute__((ext_vector_type(4))) float  floatx4;
typedef __attribute__((ext_vector_type(4))) unsigned int uintx4;
typedef __attribute__((ext_vector_type(2))) unsigned int uintx2;

// ---------------- workspace layout (bytes) ----------------
#define WS_COUNTS 0                         // 64 * i32
#define WS_BASE   256                       // 64 * i32 (exclusive prefix of counts)
#define WS_SELE   1024                      // per (t,k): expert id       [TK_]
#define WS_SELS   (WS_SELE + TK_*4)         // per (t,k): slot in expert  [TK_]
#define WS_SELW   (WS_SELS + TK_*4)         // per (t,k): softmax weight  [TK_]
#define WS_BTOK   (WS_SELW + TK_*4)         // per (e,slot): token id     [E_*T_]
#define WS_BW     (WS_BTOK + E_*T_*4)       // per (e,slot): weight       [E_*T_] (fallback path)
#define WS_TILEE  (WS_BW + E_*T_*4)         // tile -> expert id          [MAXTILES]
#define WS_TILEM  (WS_TILEE + MAXTILES*4)   // tile -> m0 within expert   [MAXTILES]
#define WS_NT     (WS_TILEM + MAXTILES*4)   // tile count (1 int, padded)
#define WS_ACT    (WS_NT + 64)              // bf16 act, packed rows, +128 rows slack for tile overread
#define ACT_ROWS  (TK_ + 128)
#define ACT_BYTES (ACT_ROWS * I_ * 2)
#define WS_DOWN   (WS_ACT + ACT_BYTES)      // fp32 down result per pair [TK_][H_]
#define DOWN_BYTES ((size_t)TK_ * H_ * 4)
#define WS_NEED_MAIN ((size_t)WS_DOWN + DOWN_BYTES)   // ~153.4 MB

// fp32 -> bf16 round-to-nearest-even (3 VALU ops; no NaN inputs here)
__device__ __forceinline__ unsigned short f2bf(float f) {
  unsigned u = __float_as_uint(f);
  return (unsigned short)((u + 0x7fffu + ((u >> 16) & 1u)) >> 16);
}
__device__ __forceinline__ unsigned f2bf2(float lo, float hi) {
  return (unsigned)f2bf(lo) | ((unsigned)f2bf(hi) << 16);
}

// Swizzled LDS layouts, row stride 64B (32 bf16), XOR on 16B chunks to keep both the
// transpose-stage writes and the b128 fragment reads at <=2-way bank conflicts.
__device__ __forceinline__ int offsA2(int r, int k) {      // A tile [BM][BK]
  return r * 64 + ((((k >> 3) ^ r) & 3) << 4) + (k & 7) * 2;
}
__device__ __forceinline__ int offsB2(int n, int k) {      // B tile transposed [BN][BK]
  return n * 64 + ((((k >> 3) ^ (n >> 2)) & 3) << 4) + (k & 7) * 2;
}

// ---------------- kernel 1: router (logits fp32, top-8, softmax, bucket by expert) ----
__global__ __launch_bounds__(64) void moe_router(
    const float* __restrict__ x, const float* __restrict__ gw,
    int* __restrict__ counts, int* __restrict__ sel_e, int* __restrict__ sel_s,
    float* __restrict__ sel_w, int* __restrict__ btok, float* __restrict__ bw)
{
  __shared__ float xs[4][512];
  const int lane = threadIdx.x;            // lane == expert id
  const int t0 = blockIdx.x * 4;
  float acc[4] = {0.f, 0.f, 0.f, 0.f};

  for (int c = 0; c < 4; ++c) {            // H in 4 chunks of 512
    __syncthreads();
    #pragma unroll
    for (int i = 0; i < 8; ++i) {          // stage 4 token rows x 512 h into LDS
      int f4 = lane + i * 64;              // 0..511 float4 slots
      int r = f4 >> 7, cc = f4 & 127;
      *(floatx4*)&xs[r][cc * 4] = *(const floatx4*)&x[(size_t)(t0 + r) * H_ + c * 512 + cc * 4];
    }
    __syncthreads();
    for (int h = 0; h < 512; ++h) {
      float g = gw[(c * 512 + h) * E_ + lane];   // coalesced 256B/wave
      acc[0] += xs[0][h] * g;
      acc[1] += xs[1][h] * g;
      acc[2] += xs[2][h] * g;
      acc[3] += xs[3][h] * g;
    }
  }

  for (int j = 0; j < 4; ++j) {
    const int t = t0 + j;
    float v0 = acc[j];
    float topv[8]; int topi[8];
    #pragma unroll
    for (int k = 0; k < 8; ++k) {          // 8x argmax via 64-lane butterfly, ties -> lowest idx
      float v = v0; int idx = lane;
      #pragma unroll
      for (int s = 32; s > 0; s >>= 1) {
        float ov = __shfl_xor(v, s);
        int   oi = __shfl_xor(idx, s);
        if (ov > v || (ov == v && oi < idx)) { v = ov; idx = oi; }
      }
      topv[k] = v; topi[k] = idx;
      if (lane == idx) v0 = -1e30f;
    }
    float m = topv[0], ssum = 0.f, w[8];
    #pragma unroll
    for (int k = 0; k < 8; ++k) { w[k] = __expf(topv[k] - m); ssum += w[k]; }
    const float inv = 1.f / ssum;
    #pragma unroll
    for (int k = 0; k < 8; ++k) {          // lane k commits pair k (static indexing)
      if (lane == k) {
        const int e = topi[k];
        const int slot = atomicAdd(&counts[e], 1);
        sel_e[t * 8 + k] = e;
        sel_s[t * 8 + k] = slot;
        sel_w[t * 8 + k] = w[k] * inv;
        btok[e * T_ + slot] = t;
        bw[e * T_ + slot] = w[k] * inv;
      }
    }
  }
}

// ---------------- kernel 2: exclusive prefix over 64 counts + compact tile list --------
__global__ void moe_prefix(const int* __restrict__ counts, int* __restrict__ base,
                           int* __restrict__ tile_e, int* __restrict__ tile_m,
                           int* __restrict__ ntiles) {
  if (threadIdx.x == 0) {
    int s = 0, nt = 0;
    for (int e = 0; e < E_; ++e) {
      base[e] = s; s += counts[e];
      for (int m0 = 0; m0 < counts[e]; m0 += BM) { tile_e[nt] = e; tile_m[nt] = m0; ++nt; }
    }
    *ntiles = nt;
  }
}

// ---------------- kernel 3: grouped gate/up GEMM + SiLU, act -> bf16 packed ----------
// grid = (I_/BN, MAXTILES); blockIdx.y indexes the dense tile list -> even CU distribution.
__global__ __launch_bounds__(256) void moe_gateup(
    const float* __restrict__ x, const float* __restrict__ gp, const float* __restrict__ up,
    const int* __restrict__ counts, const int* __restrict__ base,
    const int* __restrict__ btok,
    const int* __restrict__ tile_e, const int* __restrict__ tile_m,
    const int* __restrict__ ntiles, unsigned short* __restrict__ act)
{
  const int ti = blockIdx.y;
  if (ti >= *ntiles) return;                // dense prefix: only ~30 tail blocks exit
  const int e  = tile_e[ti];
  const int m0 = tile_m[ti];
  const int cnt = counts[e];
  const int n0 = blockIdx.x * BN;

  __shared__ unsigned char As[BM * 64];     // 8KB swizzled bf16 [128][32]
  __shared__ unsigned char Bg[BN * 64];     // 8KB transposed+swizzled [n][k]
  __shared__ unsigned char Bu[BN * 64];

  const int tid = threadIdx.x;
  const int lane = tid & 63;
  const int wr = (tid >> 6) & 1, wc = tid >> 7;  // 2x2 wave grid, 64x64 per wave

  // A staging: thread -> row ar, k-half ah (16 floats = 4 float4). Rows are gathered tokens.
  const int ar = tid >> 1, ah = tid & 1;
  int tokr = 0;
  if (m0 + ar < cnt) tokr = btok[e * T_ + m0 + ar];
  const float* aptr = x + (size_t)tokr * H_ + ah * 16;

  // B staging: thread loads 4 float4 (rows bk0..bk0+3, cols bn4*4..+3), repacks k-major.
  const int bn4 = tid & 31, bk0 = (tid >> 5) << 2;
  const size_t wbase = (size_t)e * H_ * I_;
  const float* gptr = gp + wbase + n0 + bn4 * 4;
  const float* uptr = up + wbase + n0 + bn4 * 4;

  floatx4 accg[4][4], accu[4][4];
  #pragma unroll
  for (int i = 0; i < 4; ++i)
    #pragma unroll
    for (int j = 0; j < 4; ++j) { accg[i][j] = (floatx4){0,0,0,0}; accu[i][j] = (floatx4){0,0,0,0}; }

  floatx4 Ar[4], Gr[4], Ur[4];
  #pragma unroll
  for (int i = 0; i < 4; ++i) {
    Ar[i] = *(const floatx4*)(aptr + i * 4);
    Gr[i] = *(const floatx4*)(gptr + (size_t)(bk0 + i) * I_);
    Ur[i] = *(const floatx4*)(uptr + (size_t)(bk0 + i) * I_);
  }

  const int c15 = lane & 15;
  const int kq = (lane >> 4) << 3;

  for (int kk = 0; kk < H_; kk += BK) {
    __syncthreads();
    #pragma unroll
    for (int i = 0; i < 4; ++i) {           // A: cvt + b64 writes
      uintx2 p; p.x = f2bf2(Ar[i].x, Ar[i].y); p.y = f2bf2(Ar[i].z, Ar[i].w);
      *(uintx2*)(As + offsA2(ar, ah * 16 + i * 4)) = p;
    }
    #pragma unroll
    for (int n = 0; n < 4; ++n) {           // B: transpose-repack (4 k per column) + b64 writes
      uintx2 pg; pg.x = f2bf2(Gr[0][n], Gr[1][n]); pg.y = f2bf2(Gr[2][n], Gr[3][n]);
      *(uintx2*)(Bg + offsB2(bn4 * 4 + n, bk0)) = pg;
      uintx2 pu; pu.x = f2bf2(Ur[0][n], Ur[1][n]); pu.y = f2bf2(Ur[2][n], Ur[3][n]);
      *(uintx2*)(Bu + offsB2(bn4 * 4 + n, bk0)) = pu;
    }
    __syncthreads();
    if (kk + BK < H_) {                      // prefetch next K-step (overlaps MFMA below)
      #pragma unroll
      for (int i = 0; i < 4; ++i) {
        Ar[i] = *(const floatx4*)(aptr + kk + BK + i * 4);
        Gr[i] = *(const floatx4*)(gptr + (size_t)(kk + BK + bk0 + i) * I_);
        Ur[i] = *(const floatx4*)(uptr + (size_t)(kk + BK + bk0 + i) * I_);
      }
    }
    short8 af[4];
    #pragma unroll
    for (int rt = 0; rt < 4; ++rt)
      af[rt] = *(const short8*)(As + offsA2(wr * 64 + rt * 16 + c15, kq));
    #pragma unroll
    for (int ct = 0; ct < 4; ++ct) {
      const int nn = wc * 64 + ct * 16 + c15;
      short8 bg = *(const short8*)(Bg + offsB2(nn, kq));
      short8 bu = *(const short8*)(Bu + offsB2(nn, kq));
      #pragma unroll
      for (int rt = 0; rt < 4; ++rt) {
        accg[rt][ct] = __builtin_amdgcn_mfma_f32_16x16x32_bf16(af[rt], bg, accg[rt][ct], 0, 0, 0);
        accu[rt][ct] = __builtin_amdgcn_mfma_f32_16x16x32_bf16(af[rt], bu, accu[rt][ct], 0, 0, 0);
      }
    }
  }

  // epilogue: act = silu(gate)*up -> bf16, packed rows base[e]+m0+rl
  const int cLim = cnt - m0;
  const size_t gbase = (size_t)(base[e] + m0);
  const int q = lane >> 4;
  #pragma unroll
  for (int rt = 0; rt < 4; ++rt) {
    #pragma unroll
    for (int rg = 0; rg < 4; ++rg) {
      const int rl = wr * 64 + rt * 16 + q * 4 + rg;   // C/D: row = quad*4+reg
      if (rl < cLim) {
        unsigned short* arow = act + (gbase + rl) * I_ + n0 + wc * 64 + c15;
        #pragma unroll
        for (int ct = 0; ct < 4; ++ct) {
          float g = accg[rt][ct][rg], u = accu[rt][ct][rg];
          float a = (g / (1.f + __expf(-g))) * u;
          arow[ct * 16] = f2bf(a);
        }
      }
    }
  }
}

// ---------------- kernel 4: grouped down GEMM. Main: fp32 per-pair rows. Fallback: atomics.
// grid = (H_/BN, MAXTILES); same dense tile list.
template <bool ATOMIC>
__global__ __launch_bounds__(256) void moe_down(
    const unsigned short* __restrict__ act, const float* __restrict__ dp,
    const int* __restrict__ counts, const int* __restrict__ base,
    const int* __restrict__ btok, const float* __restrict__ bw,
    const int* __restrict__ tile_e, const int* __restrict__ tile_m,
    const int* __restrict__ ntiles, float* __restrict__ outp)
{
  const int ti = blockIdx.y;
  if (ti >= *ntiles) return;
  const int e  = tile_e[ti];
  const int m0 = tile_m[ti];
  const int cnt = counts[e];
  const int n0 = blockIdx.x * BN;
  const int bas = base[e];

  __shared__ unsigned char As[BM * 64];     // LINEAR bf16 [128][32] (A already bf16, contiguous)
  __shared__ unsigned char Bs[BN * 64];
  __shared__ int   tokL[BM];
  __shared__ float wL[BM];

  const int tid = threadIdx.x;
  const int lane = tid & 63;
  const int wr = (tid >> 6) & 1, wc = tid >> 7;

  if (ATOMIC && tid < BM) {
    int tk = 0; float w = 0.f;
    if (m0 + tid < cnt) { tk = btok[e * T_ + m0 + tid]; w = bw[e * T_ + m0 + tid]; }
    tokL[tid] = tk; wL[tid] = w;
  }

  // A staging: 16B chunk per thread per half: chunk=(tid + j*256) -> r=chunk>>2, kc=chunk&3
  const int r0 = tid >> 2, kc0 = tid & 3;
  const unsigned short* a0 = act + (size_t)(bas + m0 + r0) * I_ + kc0 * 8;  // rows have +128 slack
  const unsigned short* a1 = a0 + (size_t)64 * I_;

  const int bn4 = tid & 31, bk0 = (tid >> 5) << 2;
  const float* dptr = dp + (size_t)e * I_ * H_ + n0 + bn4 * 4;

  floatx4 acc[4][4];
  #pragma unroll
  for (int i = 0; i < 4; ++i)
    #pragma unroll
    for (int j = 0; j < 4; ++j) acc[i][j] = (floatx4){0,0,0,0};

  uintx4 A0 = *(const uintx4*)a0;
  uintx4 A1 = *(const uintx4*)a1;
  floatx4 Dr[4];
  #pragma unroll
  for (int i = 0; i < 4; ++i) Dr[i] = *(const floatx4*)(dptr + (size_t)(bk0 + i) * H_);

  const int c15 = lane & 15;
  const int kq = (lane >> 4) << 3;

  for (int kk = 0; kk < I_; kk += BK) {
    __syncthreads();
    *(uintx4*)(As + tid * 16) = A0;
    *(uintx4*)(As + tid * 16 + 4096) = A1;
    #pragma unroll
    for (int n = 0; n < 4; ++n) {
      uintx2 p; p.x = f2bf2(Dr[0][n], Dr[1][n]); p.y = f2bf2(Dr[2][n], Dr[3][n]);
      *(uintx2*)(Bs + offsB2(bn4 * 4 + n, bk0)) = p;
    }
    __syncthreads();
    if (kk + BK < I_) {
      A0 = *(const uintx4*)(a0 + kk + BK);
      A1 = *(const uintx4*)(a1 + kk + BK);
      #pragma unroll
      for (int i = 0; i < 4; ++i)
        Dr[i] = *(const floatx4*)(dptr + (size_t)(kk + BK + bk0 + i) * H_);
    }
    short8 af[4];
    #pragma unroll
    for (int rt = 0; rt < 4; ++rt)
      af[rt] = *(const short8*)(As + (wr * 64 + rt * 16 + c15) * 64 + kq * 2);
    #pragma unroll
    for (int ct = 0; ct < 4; ++ct) {
      short8 bd = *(const short8*)(Bs + offsB2(wc * 64 + ct * 16 + c15, kq));
      #pragma unroll
      for (int rt = 0; rt < 4; ++rt)
        acc[rt][ct] = __builtin_amdgcn_mfma_f32_16x16x32_bf16(af[rt], bd, acc[rt][ct], 0, 0, 0);
    }
  }

  const int cLim = cnt - m0;
  const int q = lane >> 4;
  #pragma unroll
  for (int rt = 0; rt < 4; ++rt) {
    #pragma unroll
    for (int rg = 0; rg < 4; ++rg) {
      const int rl = wr * 64 + rt * 16 + q * 4 + rg;
      if (rl < cLim) {
        if (ATOMIC) {
          const float w = wL[rl];
          float* orow = outp + (size_t)tokL[rl] * H_ + n0 + wc * 64 + c15;
          #pragma unroll
          for (int ct = 0; ct < 4; ++ct)
            atomicAdd(&orow[ct * 16], w * acc[rt][ct][rg]);
        } else {
          float* drow = outp + (size_t)(bas + m0 + rl) * H_ + n0 + wc * 64 + c15;
          #pragma unroll
          for (int ct = 0; ct < 4; ++ct)
            drow[ct * 16] = acc[rt][ct][rg];
        }
      }
    }
  }
}

// ---------------- kernel 5: weighted combine of 8 pair rows per token ----------------
__global__ __launch_bounds__(256) void moe_final(
    const float* __restrict__ down, const int* __restrict__ sel_e,
    const int* __restrict__ sel_s, const float* __restrict__ sel_w,
    const int* __restrict__ base, float* __restrict__ out)
{
  const int t = blockIdx.x;
  const int tid = threadIdx.x;              // 256 threads x 8 cols = 2048
  floatx4 o0 = {0,0,0,0}, o1 = {0,0,0,0};
  #pragma unroll
  for (int k = 0; k < 8; ++k) {
    const int e = sel_e[t * 8 + k];
    const int s = sel_s[t * 8 + k];
    const float w = sel_w[t * 8 + k];
    const float* dr = down + (size_t)(base[e] + s) * H_ + tid * 8;
    floatx4 v0 = *(const floatx4*)dr;
    floatx4 v1 = *(const floatx4*)(dr + 4);
    o0 += w * v0;
    o1 += w * v1;
  }
  *(floatx4*)(out + (size_t)t * H_ + tid * 8) = o0;
  *(floatx4*)(out + (size_t)t * H_ + tid * 8 + 4) = o1;
}

extern "C" void kernel_launch(void* const* d_in, const int* in_sizes, int n_in,
                              void* d_out, int out_size, void* d_ws, size_t ws_size,
                              hipStream_t stream) {
  const float* x  = (const float*)d_in[0];   // [T, H]
  const float* gw = (const float*)d_in[1];   // [H, E]
  const float* gp = (const float*)d_in[2];   // [E, H, I]
  const float* up = (const float*)d_in[3];   // [E, H, I]
  const float* dp = (const float*)d_in[4];   // [E, I, H]
  float* out = (float*)d_out;
  char* ws = (char*)d_ws;

  int*   counts = (int*)(ws + WS_COUNTS);
  int*   basep  = (int*)(ws + WS_BASE);
  int*   sel_e  = (int*)(ws + WS_SELE);
  int*   sel_s  = (int*)(ws + WS_SELS);
  float* sel_w  = (float*)(ws + WS_SELW);
  int*   btok   = (int*)(ws + WS_BTOK);
  float* bwp    = (float*)(ws + WS_BW);
  int*   tile_e = (int*)(ws + WS_TILEE);
  int*   tile_m = (int*)(ws + WS_TILEM);
  int*   ntilep = (int*)(ws + WS_NT);
  unsigned short* act = (unsigned short*)(ws + WS_ACT);
  float* down   = (float*)(ws + WS_DOWN);

  hipMemsetAsync(ws, 0, 1024, stream);       // zero counts (+base) — ws is re-poisoned every call

  moe_router<<<T_ / 4, 64, 0, stream>>>(x, gw, counts, sel_e, sel_s, sel_w, btok, bwp);
  moe_prefix<<<1, 64, 0, stream>>>(counts, basep, tile_e, tile_m, ntilep);
  moe_gateup<<<dim3(I_ / BN, MAXTILES), 256, 0, stream>>>(x, gp, up, counts, basep, btok,
                                                          tile_e, tile_m, ntilep, act);

  if (ws_size >= WS_NEED_MAIN) {
    moe_down<false><<<dim3(H_ / BN, MAXTILES), 256, 0, stream>>>(act, dp, counts, basep, btok, bwp,
                                                                 tile_e, tile_m, ntilep, down);
    moe_final<<<T_, 256, 0, stream>>>(down, sel_e, sel_s, sel_w, basep, out);
  } else {
    hipMemsetAsync(out, 0, (size_t)T_ * H_ * 4, stream);
    moe_down<true><<<dim3(H_ / BN, MAXTILES), 256, 0, stream>>>(act, dp, counts, basep, btok, bwp,
                                                                tile_e, tile_m, ntilep, out);
  }
}